// Round 10
// baseline (393.742 us; speedup 1.0000x reference)
//
#include <hip/hip_runtime.h>
#include <hip/hip_bf16.h>

typedef __attribute__((ext_vector_type(4))) float f32x4;
typedef __attribute__((ext_vector_type(8))) short s16x8;

#define B_ 64
#define T_ 4096
#define H_ 512
#define E_ 512
#define BM 64          // T-rows per k2 block (= context chunk)
#define NCH (T_ / BM)  // 64 chunks per batch row

__device__ __forceinline__ short b2s(float x) {
  __hip_bfloat16 h = __float2bfloat16(x);  // RNE; pairs fuse to v_cvt_pk_bf16_f32
  return __builtin_bit_cast(short, h);
}

__device__ __forceinline__ s16x8 cvt8(f32x4 a, f32x4 b) {
  s16x8 r;
  r[0] = b2s(a[0]); r[1] = b2s(a[1]); r[2] = b2s(a[2]); r[3] = b2s(a[3]);
  r[4] = b2s(b[0]); r[5] = b2s(b[1]); r[6] = b2s(b[2]); r[7] = b2s(b[3]);
  return r;
}

__device__ __forceinline__ float bf2f(short s) {
  return __uint_as_float(((unsigned)(unsigned short)s) << 16);
}

__device__ __forceinline__ float fast_tanh(float x) {
  float e;
  asm("v_exp_f32 %0, %1" : "=v"(e) : "v"(x * 2.88539008177792681f));  // 2^(2x/ln2)
  float r;
  asm("v_rcp_f32 %0, %1" : "=v"(r) : "v"(e + 1.0f));
  return 1.0f - 2.0f * r;
}

// k0: fragment-major repack of W_e (rows 512..1023 of W_attn):
// frag(h16, s) is ONE contiguous 1-KiB block; lane i loads base+i*16B.
__global__ __launch_bounds__(512) void k0_fragpack(const float* __restrict__ W,
                                                   unsigned short* __restrict__ WtF) {
  const int h16 = blockIdx.x;   // 0..31
  const int s = blockIdx.y;     // 0..15
  const int tid = threadIdx.x;  // 0..511
  const int lane = tid >> 3, e = tid & 7;
  const int lr = lane & 15, lq = lane >> 4;
  const int k = s * 32 + lq * 8 + e;
  const int h = h16 * 16 + lr;
  WtF[(size_t)(h16 * 16 + s) * 512 + tid] =
      (unsigned short)b2s(W[(size_t)(512 + k) * H_ + h]);
}

// k1: projb[b][h] = b_attn[h] + sum_e hidden[b][e] * W_attn[e][h]
__global__ __launch_bounds__(512) void k1_projb(const float* __restrict__ hidden,
                                                const float* __restrict__ W,
                                                const float* __restrict__ b_attn,
                                                float* __restrict__ projb) {
  __shared__ float hid_s[H_];
  __shared__ float part[4][128];
  const int b = blockIdx.x, hg = blockIdx.y;
  const int tid = threadIdx.x;
  const int hl = tid & 127, es = tid >> 7;
  hid_s[tid] = hidden[b * H_ + tid];
  __syncthreads();
  const int h = hg * 128 + hl;
  const float* wp = W + (size_t)(es * 128) * H_ + h;
  float s = 0.0f;
  #pragma unroll 8
  for (int e = 0; e < 128; ++e) s = fmaf(hid_s[es * 128 + e], wp[(size_t)e * H_], s);
  part[es][hl] = s;
  __syncthreads();
  if (es == 0)
    projb[b * H_ + h] = b_attn[h] + part[0][hl] + part[1][hl] + part[2][hl] + part[3][hl];
}

// k2: fused logits + chunk-softmax + partial context.
// 256 thr = 4 waves; wave tile 64T x 128H, acc[4][8]=128 AGPR; 16x16x32 MFMA.
// A (enc) bf16 in LDS, filled QUARTER-PIPELINED: stage quarter q+1
// (global->reg->cvt->swizzled ds_write) during quarter q's 4 K-steps; one
// __syncthreads per quarter boundary. B from fragment-major WtF, coalesced,
// reg ping-pong. Epilogue context reads the bf16 A tile from LDS (no L2 pass).
__global__ __launch_bounds__(256, 2) void k2_logits(
    const float* __restrict__ enc, const unsigned short* __restrict__ wtF,
    const float* __restrict__ projb, const float* __restrict__ vw,
    float* __restrict__ logits, float* __restrict__ mstat,
    float* __restrict__ partial) {
  __shared__ unsigned short a_s[BM * 512];  // 64 KiB, whole-K A tile (bf16)
  __shared__ float projb_s[H_];
  __shared__ float vw_s[H_];
  __shared__ float part[BM][4];
  __shared__ float lg_s[BM];
  __shared__ float comb[3][64][8];  // 6 KiB, context combine

  const int b = blockIdx.y;
  const int chunk = blockIdx.x;
  const int t0 = chunk * BM;
  const int tid = threadIdx.x;
  const int lane = tid & 63;
  const int w = tid >> 6;  // wave id = H-slice (0..3)
  const int lr = lane & 15;
  const int lq = lane >> 4;

  projb_s[tid] = projb[b * H_ + tid];
  projb_s[tid + 256] = projb[b * H_ + tid + 256];
  vw_s[tid] = vw[tid];
  vw_s[tid + 256] = vw[tid + 256];

  const size_t row0 = (size_t)b * T_ + t0;

  // fill-stage geometry: 4 threads/row; per quarter each thread owns 4 chunks
  // (chunk = 8 bf16 = 16 B), stored swizzled at slot (c ^ (row&7)).
  const int ra = tid >> 2, ca = tid & 3;
  const float* aSrc = enc + (row0 + ra) * (size_t)E_;
  unsigned short* aRow = &a_s[ra * 512];

  // ---- prologue: stage quarter 0 (chunks 0..15) ----
  {
    f32x4 s0[8];
    #pragma unroll
    for (int j = 0; j < 4; ++j) {
      const int c = ca + 4 * j;
      s0[2 * j] = *(const f32x4*)(aSrc + c * 8);
      s0[2 * j + 1] = *(const f32x4*)(aSrc + c * 8 + 4);
    }
    #pragma unroll
    for (int j = 0; j < 4; ++j) {
      const int c = ca + 4 * j;
      *(s16x8*)&aRow[(c ^ (ra & 7)) * 8] = cvt8(s0[2 * j], s0[2 * j + 1]);
    }
  }
  __syncthreads();

  // B: fragment-major; wave w owns h16 = w*8 + nb
  const int wu = __builtin_amdgcn_readfirstlane(w);
  const unsigned short* wtW = wtF + ((size_t)wu * 8 * 16) * 512 + (size_t)lane * 8;
  const unsigned short* aBase = &a_s[0];

#define LOADB(dst, s)                                                        \
  _Pragma("unroll") for (int nb = 0; nb < 8; ++nb) dst[nb] =                 \
      *(const s16x8*)(wtW + ((size_t)(nb * 16 + (s)) << 9));
#define LOADA(dst, s)                                                        \
  _Pragma("unroll") for (int a = 0; a < 4; ++a) dst[a] =                     \
      *(const s16x8*)&aBase[(a * 16 + lr) * 512 + (((s) * 4 + lq) ^ (lr & 7)) * 8];
#define MFMA32(af, bf)                                                       \
  __builtin_amdgcn_s_setprio(1);                                             \
  _Pragma("unroll") for (int a = 0; a < 4; ++a)                              \
  _Pragma("unroll") for (int nb = 0; nb < 8; ++nb) acc[a][nb] =              \
      __builtin_amdgcn_mfma_f32_16x16x32_bf16(af[a], bf[nb], acc[a][nb], 0, 0, 0); \
  __builtin_amdgcn_s_setprio(0);
#define STAGE_ISSUE(q1, j0)                                                  \
  _Pragma("unroll") for (int j = (j0); j < (j0) + 2; ++j) {                  \
    const int c = (q1)*16 + ca + 4 * j;                                      \
    stg[2 * (j - (j0))] = *(const f32x4*)(aSrc + c * 8);                     \
    stg[2 * (j - (j0)) + 1] = *(const f32x4*)(aSrc + c * 8 + 4);             \
  }
#define STAGE_WRITE(q1, j0)                                                  \
  _Pragma("unroll") for (int j = (j0); j < (j0) + 2; ++j) {                  \
    const int c = (q1)*16 + ca + 4 * j;                                      \
    *(s16x8*)&aRow[(c ^ (ra & 7)) * 8] = cvt8(stg[2 * (j - (j0))], stg[2 * (j - (j0)) + 1]); \
  }

  f32x4 acc[4][8] = {};
  s16x8 bA[8], bB[8], aA[4], aB[4];
  f32x4 stg[4];  // one stage pair live at a time (16 VGPR)

  LOADA(aA, 0);
  LOADB(bA, 0);
  #pragma unroll
  for (int p = 0; p < 8; ++p) {
    const int s = 2 * p;
    const int q = p >> 1;
    if ((p & 1) == 0) {
      // even p = quarter q start (post-sync for p>0)
      if (p > 0) { LOADA(aA, s); }        // this step's A, this quarter (safe)
      if (q < 3) { STAGE_ISSUE(q + 1, 0); }  // pair0 for next quarter
      LOADA(aB, s + 1);
      LOADB(bB, s + 1);
      MFMA32(aA, bA);
      if (q < 3) { STAGE_WRITE(q + 1, 0); STAGE_ISSUE(q + 1, 2); }  // hold pair1
      LOADA(aA, s + 2);                  // step 4q+2, same quarter (safe)
      LOADB(bA, s + 2);
      MFMA32(aB, bB);
    } else {
      if (q < 3) { STAGE_WRITE(q + 1, 2); }  // pair1 (age ~1 step)
      LOADA(aB, s + 1);                  // step 4q+3, same quarter (safe)
      LOADB(bB, s + 1);
      MFMA32(aA, bA);
      if (p < 7) { LOADB(bA, s + 2); }   // next quarter's B (regs, no hazard)
      MFMA32(aB, bB);
      if (p < 7) __syncthreads();        // quarter boundary (p = 1,3,5)
    }
  }
#undef LOADA
#undef LOADB
#undef MFMA32
#undef STAGE_ISSUE
#undef STAGE_WRITE

  // ---- logits: energy = tanh(acc + projb), partial = sum_h energy * vw ----
  #pragma unroll
  for (int a = 0; a < 4; ++a) {
    #pragma unroll
    for (int j = 0; j < 4; ++j) {
      float ssum = 0.0f;
      #pragma unroll
      for (int nb = 0; nb < 8; ++nb) {
        const int h = w * 128 + nb * 16 + lr;  // C/D: col = lane&15
        float x = acc[a][nb][j] + projb_s[h];
        ssum += fast_tanh(x) * vw_s[h];
      }
      ssum += __shfl_xor(ssum, 1);
      ssum += __shfl_xor(ssum, 2);
      ssum += __shfl_xor(ssum, 4);
      ssum += __shfl_xor(ssum, 8);
      if (lr == 0) part[a * 16 + lq * 4 + j][w] = ssum;  // C/D: row = lq*4+j
    }
  }
  __syncthreads();
  if (tid < BM) {
    float l = part[tid][0] + part[tid][1] + part[tid][2] + part[tid][3];
    lg_s[tid] = l;
    logits[(size_t)b * T_ + t0 + tid] = l;
  }
  __syncthreads();

  // ---- chunk softmax numerator + partial context from LDS bf16 A tile ----
  float m_c = -1e30f;
  #pragma unroll 8
  for (int t = 0; t < BM; ++t) m_c = fmaxf(m_c, lg_s[t]);

  const int cc = tid & 63;  // bf16 chunk column (8 e-values)
  const int tg = tid >> 6;  // 0..3, 16 t-rows each
  float a8[8] = {};
  #pragma unroll 4
  for (int i = 0; i < 16; ++i) {
    const int r = tg * 16 + i;
    float pw = __expf(lg_s[r] - m_c);
    s16x8 av = *(const s16x8*)&a_s[r * 512 + (cc ^ (r & 7)) * 8];
    #pragma unroll
    for (int e = 0; e < 8; ++e) a8[e] = fmaf(pw, bf2f(av[e]), a8[e]);
  }
  if (tg > 0) {
    #pragma unroll
    for (int e = 0; e < 8; ++e) comb[tg - 1][cc][e] = a8[e];
  }
  __syncthreads();
  if (tg == 0) {
    float* pp = partial + ((size_t)(b * NCH + chunk)) * E_ + cc * 8;
    #pragma unroll
    for (int e = 0; e < 8; ++e)
      pp[e] = a8[e] + comb[0][cc][e] + comb[1][cc][e] + comb[2][cc][e];
    if (tid == 0) mstat[b * NCH + chunk] = m_c;
  }
}

// k3: softmax over T per batch -> weights; also per-b (max, Z)
__global__ __launch_bounds__(256) void k3_softmax(const float* __restrict__ logits,
                                                  float* __restrict__ weights,
                                                  float* __restrict__ mz) {
  __shared__ float red[4];
  const int b = blockIdx.x;
  const int tid = threadIdx.x;
  const float* lg = logits + (size_t)b * T_;
  float v[16];
  float m = -1e30f;
  #pragma unroll
  for (int i = 0; i < 16; ++i) {
    v[i] = lg[tid + i * 256];
    m = fmaxf(m, v[i]);
  }
  #pragma unroll
  for (int d = 1; d < 64; d <<= 1) m = fmaxf(m, __shfl_xor(m, d));
  if ((tid & 63) == 0) red[tid >> 6] = m;
  __syncthreads();
  m = fmaxf(fmaxf(red[0], red[1]), fmaxf(red[2], red[3]));
  __syncthreads();
  float s = 0.0f;
  #pragma unroll
  for (int i = 0; i < 16; ++i) {
    v[i] = __expf(v[i] - m);
    s += v[i];
  }
  #pragma unroll
  for (int d = 1; d < 64; d <<= 1) s += __shfl_xor(s, d);
  if ((tid & 63) == 0) red[tid >> 6] = s;
  __syncthreads();
  s = red[0] + red[1] + red[2] + red[3];
  float inv = 1.0f / s;
  #pragma unroll
  for (int i = 0; i < 16; ++i) weights[(size_t)b * T_ + tid + i * 256] = v[i] * inv;
  if (tid == 0) {
    mz[b * 2] = m;
    mz[b * 2 + 1] = s;
  }
}

// k5: context = sum_c exp(m_c - m_b) * partial[b,c,:] / Z_b
__global__ __launch_bounds__(128) void k5_ctx_final(const float* __restrict__ partial,
                                                    const float* __restrict__ mstat,
                                                    const float* __restrict__ mz,
                                                    float* __restrict__ ctx) {
  __shared__ float sc[NCH];
  const int b = blockIdx.x;
  const int tid = threadIdx.x;
  const float m_b = mz[b * 2];
  const float invZ = 1.0f / mz[b * 2 + 1];
  if (tid < NCH) sc[tid] = __expf(mstat[b * NCH + tid] - m_b);
  __syncthreads();
  const float* pp = partial + (size_t)b * NCH * E_ + tid * 4;
  f32x4 s = {};
  #pragma unroll 8
  for (int c = 0; c < NCH; ++c) s += sc[c] * (*(const f32x4*)(pp + (size_t)c * E_));
  s *= invZ;
  *(f32x4*)(ctx + (size_t)b * E_ + tid * 4) = s;
}

extern "C" void kernel_launch(void* const* d_in, const int* in_sizes, int n_in,
                              void* d_out, int out_size, void* d_ws, size_t ws_size,
                              hipStream_t stream) {
  const float* hidden = (const float*)d_in[0];
  const float* enc = (const float*)d_in[1];
  const float* W_attn = (const float*)d_in[2];
  const float* b_attn = (const float*)d_in[3];
  const float* v_w = (const float*)d_in[4];

  float* out_ctx = (float*)d_out;                  // 64*512
  float* out_w = (float*)d_out + (size_t)B_ * H_;  // 64*4096

  char* ws = (char*)d_ws;
  unsigned short* WtF = (unsigned short*)ws;     // 512 KiB (fragment-major)
  float* projb = (float*)(ws + (512 << 10));     // 128 KiB
  float* logits = (float*)(ws + (640 << 10));    // 1 MiB
  float* mstat = (float*)(ws + (1664 << 10));    // 16 KiB (64*64 chunk maxes)
  float* mz = (float*)(ws + (1700 << 10));       // 512 B  (per-b max, Z)
  float* partial = (float*)(ws + (1728 << 10));  // 8 MiB  (64*64*512 fp32)

  k0_fragpack<<<dim3(32, 16), 512, 0, stream>>>(W_attn, WtF);
  k1_projb<<<dim3(64, 4), 512, 0, stream>>>(hidden, W_attn, b_attn, projb);
  k2_logits<<<dim3(NCH, B_), 256, 0, stream>>>(enc, WtF, projb, v_w, logits, mstat, partial);
  k3_softmax<<<B_, 256, 0, stream>>>(logits, out_w, mz);
  k5_ctx_final<<<B_, 128, 0, stream>>>(partial, mstat, mz, out_ctx);
}

// Round 11
// 262.716 us; speedup vs baseline: 1.4987x; 1.4987x over previous
//
#include <hip/hip_runtime.h>
#include <hip/hip_bf16.h>

typedef __attribute__((ext_vector_type(4))) float f32x4;
typedef __attribute__((ext_vector_type(8))) short s16x8;

#define B_ 64
#define T_ 4096
#define H_ 512
#define E_ 512
#define BM 64          // T-rows per k2 block (= context chunk)
#define NCH (T_ / BM)  // 64 chunks per batch row

__device__ __forceinline__ short b2s(float x) {
  __hip_bfloat16 h = __float2bfloat16(x);  // RNE; pairs fuse to v_cvt_pk_bf16_f32
  return __builtin_bit_cast(short, h);
}

__device__ __forceinline__ s16x8 cvt8(f32x4 a, f32x4 b) {
  s16x8 r;
  r[0] = b2s(a[0]); r[1] = b2s(a[1]); r[2] = b2s(a[2]); r[3] = b2s(a[3]);
  r[4] = b2s(b[0]); r[5] = b2s(b[1]); r[6] = b2s(b[2]); r[7] = b2s(b[3]);
  return r;
}

__device__ __forceinline__ float bf2f(short s) {
  return __uint_as_float(((unsigned)(unsigned short)s) << 16);
}

__device__ __forceinline__ float fast_tanh(float x) {
  float e;
  asm("v_exp_f32 %0, %1" : "=v"(e) : "v"(x * 2.88539008177792681f));  // 2^(2x/ln2)
  float r;
  asm("v_rcp_f32 %0, %1" : "=v"(r) : "v"(e + 1.0f));
  return 1.0f - 2.0f * r;
}

// k0: fragment-major repack of W_e (rows 512..1023 of W_attn):
// frag(h16, s) is ONE contiguous 1-KiB block; lane i loads base+i*16B.
__global__ __launch_bounds__(512) void k0_fragpack(const float* __restrict__ W,
                                                   unsigned short* __restrict__ WtF) {
  const int h16 = blockIdx.x;   // 0..31
  const int s = blockIdx.y;     // 0..15
  const int tid = threadIdx.x;  // 0..511
  const int lane = tid >> 3, e = tid & 7;
  const int lr = lane & 15, lq = lane >> 4;
  const int k = s * 32 + lq * 8 + e;
  const int h = h16 * 16 + lr;
  WtF[(size_t)(h16 * 16 + s) * 512 + tid] =
      (unsigned short)b2s(W[(size_t)(512 + k) * H_ + h]);
}

// k1: projb[b][h] = b_attn[h] + sum_e hidden[b][e] * W_attn[e][h]
__global__ __launch_bounds__(512) void k1_projb(const float* __restrict__ hidden,
                                                const float* __restrict__ W,
                                                const float* __restrict__ b_attn,
                                                float* __restrict__ projb) {
  __shared__ float hid_s[H_];
  __shared__ float part[4][128];
  const int b = blockIdx.x, hg = blockIdx.y;
  const int tid = threadIdx.x;
  const int hl = tid & 127, es = tid >> 7;
  hid_s[tid] = hidden[b * H_ + tid];
  __syncthreads();
  const int h = hg * 128 + hl;
  const float* wp = W + (size_t)(es * 128) * H_ + h;
  float s = 0.0f;
  #pragma unroll 8
  for (int e = 0; e < 128; ++e) s = fmaf(hid_s[es * 128 + e], wp[(size_t)e * H_], s);
  part[es][hl] = s;
  __syncthreads();
  if (es == 0)
    projb[b * H_ + h] = b_attn[h] + part[0][hl] + part[1][hl] + part[2][hl] + part[3][hl];
}

// k2: fused logits + chunk-softmax + partial context.
// 256 thr = 4 waves; block = 64T x 512H; wave tile 64T x 128H, acc[4][8]=128 AGPR.
// A (enc, 64x512) converted to bf16 and staged in LDS ONCE for the whole K
// extent (64 KB, XOR-swizzled chunk^=(row&7)). 16-step K-loop, ZERO barriers,
// ping-pong register sets; B loads from fragment-major WtF: each LOADB is one
// coalesced 1-KiB transaction. Epilogue context reads the bf16 A tile from LDS
// (no second enc pass -- R10 showed the re-read cost 128 MB of HBM).
__global__ __launch_bounds__(256, 2) void k2_logits(
    const float* __restrict__ enc, const unsigned short* __restrict__ wtF,
    const float* __restrict__ projb, const float* __restrict__ vw,
    float* __restrict__ logits, float* __restrict__ mstat,
    float* __restrict__ partial) {
  __shared__ unsigned short a_s[BM * 512];  // 64 KiB, whole-K A tile (bf16)
  __shared__ float projb_s[H_];
  __shared__ float vw_s[H_];
  __shared__ float part[BM][4];
  __shared__ float lg_s[BM];
  __shared__ float comb[3][64][8];  // 6 KiB, context combine

  const int b = blockIdx.y;
  const int chunk = blockIdx.x;
  const int t0 = chunk * BM;
  const int tid = threadIdx.x;
  const int lane = tid & 63;
  const int w = tid >> 6;  // wave id = H-slice (0..3)
  const int lr = lane & 15;
  const int lq = lane >> 4;

  projb_s[tid] = projb[b * H_ + tid];
  projb_s[tid + 256] = projb[b * H_ + tid + 256];
  vw_s[tid] = vw[tid];
  vw_s[tid + 256] = vw[tid + 256];

  const size_t row0 = (size_t)b * T_ + t0;

  // ---- fill A tile (once): 4 threads/row, 16 chunks (16B bf16) per thread ----
  {
    const int ra = tid >> 2, ca = tid & 3;
    const float* arow = enc + (row0 + ra) * (size_t)E_;
    unsigned short* adst = &a_s[ra * 512];
    #pragma unroll
    for (int jj = 0; jj < 16; ++jj) {
      const int c = ca + jj * 4;  // 16B chunk 0..63
      f32x4 v0 = *(const f32x4*)(arow + c * 8);
      f32x4 v1 = *(const f32x4*)(arow + c * 8 + 4);
      *(s16x8*)&adst[(c ^ (ra & 7)) * 8] = cvt8(v0, v1);
    }
  }
  __syncthreads();  // the ONLY pre-epilogue barrier

  // B: fragment-major; wave w owns h16 = w*8 + nb
  const int wu = __builtin_amdgcn_readfirstlane(w);
  const unsigned short* wtW = wtF + ((size_t)wu * 8 * 16) * 512 + (size_t)lane * 8;
  const unsigned short* aBase = &a_s[0];

#define LOADB(dst, s)                                                        \
  _Pragma("unroll") for (int nb = 0; nb < 8; ++nb) dst[nb] =                 \
      *(const s16x8*)(wtW + ((size_t)(nb * 16 + (s)) << 9));
#define LOADA(dst, s)                                                        \
  _Pragma("unroll") for (int a = 0; a < 4; ++a) dst[a] =                     \
      *(const s16x8*)&aBase[(a * 16 + lr) * 512 + (((s) * 4 + lq) ^ (lr & 7)) * 8];
#define MFMA32(af, bf)                                                       \
  __builtin_amdgcn_s_setprio(1);                                             \
  _Pragma("unroll") for (int a = 0; a < 4; ++a)                              \
  _Pragma("unroll") for (int nb = 0; nb < 8; ++nb) acc[a][nb] =              \
      __builtin_amdgcn_mfma_f32_16x16x32_bf16(af[a], bf[nb], acc[a][nb], 0, 0, 0); \
  __builtin_amdgcn_s_setprio(0);

  f32x4 acc[4][8] = {};
  s16x8 bA[8], bB[8], aA[4], aB[4];

  LOADA(aA, 0);
  LOADB(bA, 0);
  #pragma unroll
  for (int p = 0; p < 8; ++p) {
    const int s = 2 * p;
    LOADA(aB, s + 1);  // prefetch next step (counted waits only, no drain)
    LOADB(bB, s + 1);
    MFMA32(aA, bA);
    if (p < 7) {
      LOADA(aA, s + 2);
      LOADB(bA, s + 2);
    }
    MFMA32(aB, bB);
  }
#undef LOADA
#undef LOADB
#undef MFMA32

  // ---- logits: energy = tanh(acc + projb), partial = sum_h energy * vw ----
  #pragma unroll
  for (int a = 0; a < 4; ++a) {
    #pragma unroll
    for (int j = 0; j < 4; ++j) {
      float ssum = 0.0f;
      #pragma unroll
      for (int nb = 0; nb < 8; ++nb) {
        const int h = w * 128 + nb * 16 + lr;  // C/D: col = lane&15
        float x = acc[a][nb][j] + projb_s[h];
        ssum += fast_tanh(x) * vw_s[h];
      }
      ssum += __shfl_xor(ssum, 1);
      ssum += __shfl_xor(ssum, 2);
      ssum += __shfl_xor(ssum, 4);
      ssum += __shfl_xor(ssum, 8);
      if (lr == 0) part[a * 16 + lq * 4 + j][w] = ssum;  // C/D: row = lq*4+j
    }
  }
  __syncthreads();
  if (tid < BM) {
    float l = part[tid][0] + part[tid][1] + part[tid][2] + part[tid][3];
    lg_s[tid] = l;
    logits[(size_t)b * T_ + t0 + tid] = l;
  }
  __syncthreads();

  // ---- chunk softmax numerator + partial context from LDS bf16 A tile ----
  float m_c = -1e30f;
  #pragma unroll 8
  for (int t = 0; t < BM; ++t) m_c = fmaxf(m_c, lg_s[t]);

  const int cc = tid & 63;  // bf16 chunk column (8 e-values)
  const int tg = tid >> 6;  // 0..3, 16 t-rows each
  float a8[8] = {};
  #pragma unroll 4
  for (int i = 0; i < 16; ++i) {
    const int r = tg * 16 + i;
    float pw = __expf(lg_s[r] - m_c);
    s16x8 av = *(const s16x8*)&a_s[r * 512 + (cc ^ (r & 7)) * 8];
    #pragma unroll
    for (int e = 0; e < 8; ++e) a8[e] = fmaf(pw, bf2f(av[e]), a8[e]);
  }
  if (tg > 0) {
    #pragma unroll
    for (int e = 0; e < 8; ++e) comb[tg - 1][cc][e] = a8[e];
  }
  __syncthreads();
  if (tg == 0) {
    float* pp = partial + ((size_t)(b * NCH + chunk)) * E_ + cc * 8;
    #pragma unroll
    for (int e = 0; e < 8; ++e)
      pp[e] = a8[e] + comb[0][cc][e] + comb[1][cc][e] + comb[2][cc][e];
    if (tid == 0) mstat[b * NCH + chunk] = m_c;
  }
}

// k3: softmax over T per batch -> weights; also per-b (max, Z)
__global__ __launch_bounds__(256) void k3_softmax(const float* __restrict__ logits,
                                                  float* __restrict__ weights,
                                                  float* __restrict__ mz) {
  __shared__ float red[4];
  const int b = blockIdx.x;
  const int tid = threadIdx.x;
  const float* lg = logits + (size_t)b * T_;
  float v[16];
  float m = -1e30f;
  #pragma unroll
  for (int i = 0; i < 16; ++i) {
    v[i] = lg[tid + i * 256];
    m = fmaxf(m, v[i]);
  }
  #pragma unroll
  for (int d = 1; d < 64; d <<= 1) m = fmaxf(m, __shfl_xor(m, d));
  if ((tid & 63) == 0) red[tid >> 6] = m;
  __syncthreads();
  m = fmaxf(fmaxf(red[0], red[1]), fmaxf(red[2], red[3]));
  __syncthreads();
  float s = 0.0f;
  #pragma unroll
  for (int i = 0; i < 16; ++i) {
    v[i] = __expf(v[i] - m);
    s += v[i];
  }
  #pragma unroll
  for (int d = 1; d < 64; d <<= 1) s += __shfl_xor(s, d);
  if ((tid & 63) == 0) red[tid >> 6] = s;
  __syncthreads();
  s = red[0] + red[1] + red[2] + red[3];
  float inv = 1.0f / s;
  #pragma unroll
  for (int i = 0; i < 16; ++i) weights[(size_t)b * T_ + tid + i * 256] = v[i] * inv;
  if (tid == 0) {
    mz[b * 2] = m;
    mz[b * 2 + 1] = s;
  }
}

// k5: context = sum_c exp(m_c - m_b) * partial[b,c,:] / Z_b
__global__ __launch_bounds__(128) void k5_ctx_final(const float* __restrict__ partial,
                                                    const float* __restrict__ mstat,
                                                    const float* __restrict__ mz,
                                                    float* __restrict__ ctx) {
  __shared__ float sc[NCH];
  const int b = blockIdx.x;
  const int tid = threadIdx.x;
  const float m_b = mz[b * 2];
  const float invZ = 1.0f / mz[b * 2 + 1];
  if (tid < NCH) sc[tid] = __expf(mstat[b * NCH + tid] - m_b);
  __syncthreads();
  const float* pp = partial + (size_t)b * NCH * E_ + tid * 4;
  f32x4 s = {};
  #pragma unroll 8
  for (int c = 0; c < NCH; ++c) s += sc[c] * (*(const f32x4*)(pp + (size_t)c * E_));
  s *= invZ;
  *(f32x4*)(ctx + (size_t)b * E_ + tid * 4) = s;
}

extern "C" void kernel_launch(void* const* d_in, const int* in_sizes, int n_in,
                              void* d_out, int out_size, void* d_ws, size_t ws_size,
                              hipStream_t stream) {
  const float* hidden = (const float*)d_in[0];
  const float* enc = (const float*)d_in[1];
  const float* W_attn = (const float*)d_in[2];
  const float* b_attn = (const float*)d_in[3];
  const float* v_w = (const float*)d_in[4];

  float* out_ctx = (float*)d_out;                  // 64*512
  float* out_w = (float*)d_out + (size_t)B_ * H_;  // 64*4096

  char* ws = (char*)d_ws;
  unsigned short* WtF = (unsigned short*)ws;     // 512 KiB (fragment-major)
  float* projb = (float*)(ws + (512 << 10));     // 128 KiB
  float* logits = (float*)(ws + (640 << 10));    // 1 MiB
  float* mstat = (float*)(ws + (1664 << 10));    // 16 KiB (64*64 chunk maxes)
  float* mz = (float*)(ws + (1700 << 10));       // 512 B  (per-b max, Z)
  float* partial = (float*)(ws + (1728 << 10));  // 8 MiB  (64*64*512 fp32)

  k0_fragpack<<<dim3(32, 16), 512, 0, stream>>>(W_attn, WtF);
  k1_projb<<<dim3(64, 4), 512, 0, stream>>>(hidden, W_attn, b_attn, projb);
  k2_logits<<<dim3(NCH, B_), 256, 0, stream>>>(enc, WtF, projb, v_w, logits, mstat, partial);
  k3_softmax<<<B_, 256, 0, stream>>>(logits, out_w, mz);
  k5_ctx_final<<<B_, 128, 0, stream>>>(partial, mstat, mz, out_ctx);
}